// Round 1
// baseline (177.969 us; speedup 1.0000x reference)
//
#include <hip/hip_runtime.h>

typedef unsigned short u16;
typedef __bf16 bf16x8 __attribute__((ext_vector_type(8)));
typedef float f32x4 __attribute__((ext_vector_type(4)));
typedef u16 u16x8 __attribute__((ext_vector_type(8)));

#define MFMA16(a, b, c) __builtin_amdgcn_mfma_f32_16x16x32_bf16((a), (b), (c), 0, 0, 0)

__device__ __forceinline__ u16 f2bf(float f) {
    unsigned int u = __float_as_uint(f);
    u = (u + 0x7FFF + ((u >> 16) & 1)) >> 16;
    return (u16)u;
}

__device__ __forceinline__ void gld_lds16(const u16* g, u16* l) {
    __builtin_amdgcn_global_load_lds(
        (const __attribute__((address_space(1))) unsigned int*)g,
        (__attribute__((address_space(3))) unsigned int*)l, 16, 0, 0);
}

// ---------------- fp32 -> bf16 cast ----------------
__global__ __launch_bounds__(256) void cvt_bf16(const float* __restrict__ in,
                                                u16* __restrict__ out, int n4) {
    int idx = blockIdx.x * blockDim.x + threadIdx.x;
    int stride = gridDim.x * blockDim.x;
    for (int i = idx; i < n4; i += stride) {
        float4 v = reinterpret_cast<const float4*>(in)[i];
        ushort4 o;
        o.x = f2bf(v.x); o.y = f2bf(v.y); o.z = f2bf(v.z); o.w = f2bf(v.w);
        reinterpret_cast<ushort4*>(out)[i] = o;
    }
}

// ---------------- bf16 GEMM: C[M,N] = A[M,K] * B[N,K]^T (fp32 out) ----------------
// m97 structure: 128x128 tile, BK=32, 4 waves, global_load_lds, 2-phase loop.
__global__ __launch_bounds__(256) void gemm_bt(const u16* __restrict__ A,
                                               const u16* __restrict__ B,
                                               float* __restrict__ C,
                                               int M, int N, int K) {
    __shared__ __align__(16) u16 As[2][128 * 32];
    __shared__ __align__(16) u16 Bs[2][128 * 32];

    int nbn = N >> 7;
    int nwg = (M >> 7) * nbn;
    int bid = blockIdx.x;
    int cpx = nwg >> 3;                      // grids are %8==0
    int wg = (bid & 7) * cpx + (bid >> 3);   // XCD swizzle (bijective)
    int tm = wg / nbn, tn = wg % nbn;
    int m0 = tm << 7, n0 = tn << 7;

    int t = threadIdx.x;
    int w = t >> 6, l = t & 63, lrow = l & 15, lhi = l >> 4;
    int wr = w >> 1, wc = w & 1;

    int e0 = t * 8;              // staging elem offset, round 0
    int row0 = e0 >> 5, col0 = e0 & 31;

    const u16* Ag = A + (size_t)m0 * K;
    const u16* Bg = B + (size_t)n0 * K;

    auto stage = [&](int sbuf, int kt) {
        int k0 = kt << 5;
        gld_lds16(Ag + (size_t)row0 * K + k0 + col0, &As[sbuf][e0]);
        gld_lds16(Ag + (size_t)(row0 + 64) * K + k0 + col0, &As[sbuf][e0 + 2048]);
        gld_lds16(Bg + (size_t)row0 * K + k0 + col0, &Bs[sbuf][e0]);
        gld_lds16(Bg + (size_t)(row0 + 64) * K + k0 + col0, &Bs[sbuf][e0 + 2048]);
    };

    f32x4 acc[4][4] = {};
    int NT = K >> 5;
    stage(0, 0);
    __syncthreads();
    int buf = 0;
    for (int kt = 0; kt < NT; ++kt) {
        if (kt + 1 < NT) stage(buf ^ 1, kt + 1);
        bf16x8 af[4], bfr[4];
#pragma unroll
        for (int i = 0; i < 4; ++i) {
            af[i]  = *(const bf16x8*)&As[buf][(wr * 64 + i * 16 + lrow) * 32 + lhi * 8];
            bfr[i] = *(const bf16x8*)&Bs[buf][(wc * 64 + i * 16 + lrow) * 32 + lhi * 8];
        }
#pragma unroll
        for (int i = 0; i < 4; ++i)
#pragma unroll
            for (int j = 0; j < 4; ++j)
                acc[i][j] = MFMA16(af[i], bfr[j], acc[i][j]);
        __syncthreads();
        buf ^= 1;
    }
#pragma unroll
    for (int i = 0; i < 4; ++i) {
#pragma unroll
        for (int j = 0; j < 4; ++j) {
            int crow = m0 + wr * 64 + i * 16 + lhi * 4;
            int ccol = n0 + wc * 64 + j * 16 + lrow;
            float* cp = C + (size_t)crow * N + ccol;
#pragma unroll
            for (int r2 = 0; r2 < 4; ++r2) cp[(size_t)r2 * N] = acc[i][j][r2];
        }
    }
}

// ---------------- qkv post: RMSNorm + RoPE + cast + head-major layout ----------------
// qkv: [2048][3072] fp32. heads: q=0..31, k=32..39, v=40..47
__global__ __launch_bounds__(256) void qkv_post(const float* __restrict__ qkv,
                                                const float* __restrict__ qw,
                                                const float* __restrict__ kw,
                                                u16* __restrict__ qb,
                                                u16* __restrict__ kb,
                                                u16* __restrict__ vb) {
    int s = blockIdx.x;
    int t = threadIdx.x, w = t >> 6, lane = t & 63;
    const float* row = qkv + (size_t)s * 3072;
    int d2 = lane & 31;
    // inv_freq = 10000^(-d2/32) = 2^(-d2 * log2(10000)/32)
    float inv = exp2f(-(float)d2 * (13.287712379549449f / 32.0f));
    float ang = (float)s * inv;
    float cs = cosf(ang), sn = sinf(ang);
    for (int h = w; h < 48; h += 4) {
        float v = row[h * 64 + lane];
        if (h < 40) {
            float ss = v * v;
#pragma unroll
            for (int m = 32; m; m >>= 1) ss += __shfl_xor(ss, m);
            float rms = rsqrtf(ss * (1.0f / 64.0f) + 1e-6f);
            float wgt = (h < 32) ? qw[lane] : kw[lane];
            v = v * rms * wgt;
            float part = __shfl_xor(v, 32);
            float rot = (lane < 32) ? -part : part;
            v = v * cs + rot * sn;
            if (h < 32)
                qb[((size_t)h * 2048 + s) * 64 + lane] = f2bf(v);
            else
                kb[((size_t)(h - 32) * 2048 + s) * 64 + lane] = f2bf(v);
        } else {
            vb[((size_t)(h - 40) * 2048 + s) * 64 + lane] = f2bf(v);
        }
    }
}

// ---------------- V transpose: vb[kv][s][d] -> vt[kv][d][s] ----------------
__global__ __launch_bounds__(256) void transpose_v(const u16* __restrict__ vb,
                                                   u16* __restrict__ vt) {
    int kv = blockIdx.y;
    int s0 = blockIdx.x * 256;
    __shared__ __align__(16) u16 tile[64][256];
    int t = threadIdx.x;
    int sl = t >> 3;
    int d0 = (t & 7) * 8;
#pragma unroll
    for (int j = 0; j < 8; ++j) {
        int s = sl + j * 32;
        u16x8 v = *(const u16x8*)(vb + ((size_t)kv * 2048 + s0 + s) * 64 + d0);
#pragma unroll
        for (int e = 0; e < 8; ++e) tile[d0 + e][s] = v[e];
    }
    __syncthreads();
    int d = t >> 2;
    int so = (t & 3) * 64;
#pragma unroll
    for (int j = 0; j < 8; ++j) {
        int s_local = so + j * 8;
        *(u16x8*)(vt + ((size_t)kv * 64 + d) * 2048 + s0 + s_local) =
            *(const u16x8*)&tile[d][s_local];
    }
}

// ---------------- flash attention, sliding window 512, GQA 4:1 ----------------
// qb: [32][2048][64], kb: [8][2048][64], vt: [8][64][2048], ab: [2048][2048] (bf16)
__global__ __launch_bounds__(256) void attn_fa(const u16* __restrict__ qb,
                                               const u16* __restrict__ kb,
                                               const u16* __restrict__ vt,
                                               u16* __restrict__ ab) {
    constexpr float SCALE = 0.125f;  // 64^-0.5
    int h = blockIdx.y, qt = blockIdx.x;
    int t = threadIdx.x, w = t >> 6, l = t & 63, lrow = l & 15, lhi = l >> 4;
    int kv = h >> 2;
    int q0 = qt * 64 + w * 16;
    __shared__ __align__(16) u16 Plds[4][16][32];

    const u16* qptr = qb + ((size_t)h * 2048 + q0 + lrow) * 64 + lhi * 8;
    bf16x8 qf0 = *(const bf16x8*)qptr;
    bf16x8 qf1 = *(const bf16x8*)(qptr + 32);

    f32x4 o0 = {}, o1 = {}, o2 = {}, o3 = {};
    float mrun[4] = {0.f, 0.f, 0.f, 0.f};   // clamp max at 0: |scores|<=8 so exp safe
    float lsum[4] = {0.f, 0.f, 0.f, 0.f};

    int lo = q0 - 511; if (lo < 0) lo = 0;
    int kt0 = lo >> 5;
    int kt1 = (q0 + 15) >> 5;
    for (int kt = kt0; kt <= kt1; ++kt) {
        int jk = kt * 32;
        const u16* kbase = kb + ((size_t)kv * 2048 + jk + lrow) * 64 + lhi * 8;
        bf16x8 k00 = *(const bf16x8*)(kbase);
        bf16x8 k01 = *(const bf16x8*)(kbase + 32);
        bf16x8 k10 = *(const bf16x8*)(kbase + 16 * 64);
        bf16x8 k11 = *(const bf16x8*)(kbase + 16 * 64 + 32);
        f32x4 s0 = {}, s1 = {};
        s0 = MFMA16(qf0, k00, s0);
        s0 = MFMA16(qf1, k01, s0);
        s1 = MFMA16(qf0, k10, s1);
        s1 = MFMA16(qf1, k11, s1);

        float p0a[4], p1a[4];
#pragma unroll
        for (int i = 0; i < 4; ++i) {
            int qrow = q0 + lhi * 4 + i;
            int c0 = jk + lrow, c1 = jk + 16 + lrow;
            float v0 = s0[i] * SCALE, v1 = s1[i] * SCALE;
            bool ok0 = (qrow >= c0) && (qrow - c0 < 512);
            bool ok1 = (qrow >= c1) && (qrow - c1 < 512);
            v0 = ok0 ? v0 : -1e30f;
            v1 = ok1 ? v1 : -1e30f;
            float tm = fmaxf(v0, v1);
#pragma unroll
            for (int mm = 8; mm; mm >>= 1) tm = fmaxf(tm, __shfl_xor(tm, mm));
            float mn = fmaxf(mrun[i], tm);
            float sf = __expf(mrun[i] - mn);
            float p0 = __expf(v0 - mn), p1 = __expf(v1 - mn);
            float rs = p0 + p1;
#pragma unroll
            for (int mm = 8; mm; mm >>= 1) rs += __shfl_xor(rs, mm);
            lsum[i] = lsum[i] * sf + rs;
            mrun[i] = mn;
            o0[i] *= sf; o1[i] *= sf; o2[i] *= sf; o3[i] *= sf;
            p0a[i] = p0; p1a[i] = p1;
        }
#pragma unroll
        for (int i = 0; i < 4; ++i) {
            Plds[w][lhi * 4 + i][lrow] = f2bf(p0a[i]);
            Plds[w][lhi * 4 + i][16 + lrow] = f2bf(p1a[i]);
        }
        asm volatile("s_waitcnt lgkmcnt(0)" ::: "memory");
        bf16x8 pa = *(const bf16x8*)&Plds[w][lrow][lhi * 8];
        const u16* vbase = vt + ((size_t)kv * 64 + lrow) * 2048 + jk + lhi * 8;
        bf16x8 v0f = *(const bf16x8*)(vbase);
        bf16x8 v1f = *(const bf16x8*)(vbase + 16 * 2048);
        bf16x8 v2f = *(const bf16x8*)(vbase + 32 * 2048);
        bf16x8 v3f = *(const bf16x8*)(vbase + 48 * 2048);
        o0 = MFMA16(pa, v0f, o0);
        o1 = MFMA16(pa, v1f, o1);
        o2 = MFMA16(pa, v2f, o2);
        o3 = MFMA16(pa, v3f, o3);
    }
#pragma unroll
    for (int i = 0; i < 4; ++i) {
        float rl = 1.0f / lsum[i];
        size_t orow = (size_t)(q0 + lhi * 4 + i) * 2048 + h * 64;
        ab[orow + lrow] = f2bf(o0[i] * rl);
        ab[orow + 16 + lrow] = f2bf(o1[i] * rl);
        ab[orow + 32 + lrow] = f2bf(o2[i] * rl);
        ab[orow + 48 + lrow] = f2bf(o3[i] * rl);
    }
}

// ---------------- launch ----------------
extern "C" void kernel_launch(void* const* d_in, const int* in_sizes, int n_in,
                              void* d_out, int out_size, void* d_ws, size_t ws_size,
                              hipStream_t stream) {
    const float* x     = (const float*)d_in[0];
    const float* w_qkv = (const float*)d_in[1];
    const float* w_out = (const float*)d_in[2];
    const float* qw    = (const float*)d_in[3];
    const float* kw    = (const float*)d_in[4];
    float* out = (float*)d_out;

    char* ws = (char*)d_ws;
    // region A (8MB): x_b, later attn_b.  region B (12MB): wqkv_b, later wout_b.
    u16*   x_b    = (u16*)(ws);
    u16*   wB     = (u16*)(ws + 8388608);
    float* qkv    = (float*)(ws + 20971520);   // 24MB
    u16*   q_b    = (u16*)(ws + 46137344);     // 8MB
    u16*   k_b    = (u16*)(ws + 54525952);     // 2MB
    u16*   v_b    = (u16*)(ws + 56623104);     // 2MB
    u16*   v_t    = (u16*)(ws + 58720256);     // 2MB, end 60817408
    u16*   attn_b = x_b;

    cvt_bf16<<<2048, 256, 0, stream>>>(x, x_b, 2048 * 2048 / 4);
    cvt_bf16<<<2048, 256, 0, stream>>>(w_qkv, wB, 3072 * 2048 / 4);
    gemm_bt<<<384, 256, 0, stream>>>(x_b, wB, qkv, 2048, 3072, 2048);
    qkv_post<<<2048, 256, 0, stream>>>(qkv, qw, kw, q_b, k_b, v_b);
    transpose_v<<<dim3(8, 8), 256, 0, stream>>>(v_b, v_t);
    attn_fa<<<dim3(32, 32), 256, 0, stream>>>(q_b, k_b, v_t, attn_b);
    cvt_bf16<<<2048, 256, 0, stream>>>(w_out, wB, 2048 * 2048 / 4);
    gemm_bt<<<256, 256, 0, stream>>>(attn_b, wB, out, 2048, 2048, 2048);
}

// Round 3
// 149.482 us; speedup vs baseline: 1.1906x; 1.1906x over previous
//
#include <hip/hip_runtime.h>

typedef unsigned short u16;
typedef unsigned int u32;
typedef __bf16 bf16x8 __attribute__((ext_vector_type(8)));
typedef float f32x4 __attribute__((ext_vector_type(4)));
typedef float f32x16 __attribute__((ext_vector_type(16)));
typedef u16 u16x8 __attribute__((ext_vector_type(8)));
typedef u32 u32x2 __attribute__((ext_vector_type(2)));

#define MFMA16(a, b, c) __builtin_amdgcn_mfma_f32_16x16x32_bf16((a), (b), (c), 0, 0, 0)
#define MFMA32(a, b, c) __builtin_amdgcn_mfma_f32_32x32x16_bf16((a), (b), (c), 0, 0, 0)

__device__ __forceinline__ u16 f2bf(float f) {
    unsigned int u = __float_as_uint(f);
    u = (u + 0x7FFF + ((u >> 16) & 1)) >> 16;
    return (u16)u;
}

__device__ __forceinline__ u32 cvtpk(float a, float b) {
    u32 d;
    asm("v_cvt_pk_bf16_f32 %0, %1, %2" : "=v"(d) : "v"(a), "v"(b));
    return d;
}

__device__ __forceinline__ void gld_lds16(const u16* g, u16* l) {
    __builtin_amdgcn_global_load_lds(
        (const __attribute__((address_space(1))) unsigned int*)g,
        (__attribute__((address_space(3))) unsigned int*)l, 16, 0, 0);
}

// ---------------- fp32 -> bf16 cast ----------------
__global__ __launch_bounds__(256) void cvt_bf16(const float* __restrict__ in,
                                                u16* __restrict__ out, int n4) {
    int idx = blockIdx.x * blockDim.x + threadIdx.x;
    int stride = gridDim.x * blockDim.x;
    for (int i = idx; i < n4; i += stride) {
        float4 v = reinterpret_cast<const float4*>(in)[i];
        ushort4 o;
        o.x = f2bf(v.x); o.y = f2bf(v.y); o.z = f2bf(v.z); o.w = f2bf(v.w);
        reinterpret_cast<ushort4*>(out)[i] = o;
    }
}

// ---------------- bf16 GEMM: C[M,N] = A[M,K] * B[N,K]^T (fp32 out) ----------------
__global__ __launch_bounds__(256) void gemm_bt(const u16* __restrict__ A,
                                               const u16* __restrict__ B,
                                               float* __restrict__ C,
                                               int M, int N, int K) {
    __shared__ __align__(16) u16 As[2][128 * 32];
    __shared__ __align__(16) u16 Bs[2][128 * 32];

    int nbn = N >> 7;
    int nwg = (M >> 7) * nbn;
    int bid = blockIdx.x;
    int cpx = nwg >> 3;
    int wg = (bid & 7) * cpx + (bid >> 3);
    int tm = wg / nbn, tn = wg % nbn;
    int m0 = tm << 7, n0 = tn << 7;

    int t = threadIdx.x;
    int w = t >> 6, l = t & 63, lrow = l & 15, lhi = l >> 4;
    int wr = w >> 1, wc = w & 1;

    int e0 = t * 8;
    int row0 = e0 >> 5, col0 = e0 & 31;

    const u16* Ag = A + (size_t)m0 * K;
    const u16* Bg = B + (size_t)n0 * K;

    auto stage = [&](int sbuf, int kt) {
        int k0 = kt << 5;
        gld_lds16(Ag + (size_t)row0 * K + k0 + col0, &As[sbuf][e0]);
        gld_lds16(Ag + (size_t)(row0 + 64) * K + k0 + col0, &As[sbuf][e0 + 2048]);
        gld_lds16(Bg + (size_t)row0 * K + k0 + col0, &Bs[sbuf][e0]);
        gld_lds16(Bg + (size_t)(row0 + 64) * K + k0 + col0, &Bs[sbuf][e0 + 2048]);
    };

    f32x4 acc[4][4] = {};
    int NT = K >> 5;
    stage(0, 0);
    __syncthreads();
    int buf = 0;
    for (int kt = 0; kt < NT; ++kt) {
        if (kt + 1 < NT) stage(buf ^ 1, kt + 1);
        bf16x8 af[4], bfr[4];
#pragma unroll
        for (int i = 0; i < 4; ++i) {
            af[i]  = *(const bf16x8*)&As[buf][(wr * 64 + i * 16 + lrow) * 32 + lhi * 8];
            bfr[i] = *(const bf16x8*)&Bs[buf][(wc * 64 + i * 16 + lrow) * 32 + lhi * 8];
        }
#pragma unroll
        for (int i = 0; i < 4; ++i)
#pragma unroll
            for (int j = 0; j < 4; ++j)
                acc[i][j] = MFMA16(af[i], bfr[j], acc[i][j]);
        __syncthreads();
        buf ^= 1;
    }
#pragma unroll
    for (int i = 0; i < 4; ++i) {
#pragma unroll
        for (int j = 0; j < 4; ++j) {
            int crow = m0 + wr * 64 + i * 16 + lhi * 4;
            int ccol = n0 + wc * 64 + j * 16 + lrow;
            float* cp = C + (size_t)crow * N + ccol;
#pragma unroll
            for (int r2 = 0; r2 < 4; ++r2) cp[(size_t)r2 * N] = acc[i][j][r2];
        }
    }
}

// ---------------- qkv post: RMSNorm + RoPE + cast + head-major layout ----------------
__global__ __launch_bounds__(256) void qkv_post(const float* __restrict__ qkv,
                                                const float* __restrict__ qw,
                                                const float* __restrict__ kw,
                                                u16* __restrict__ qb,
                                                u16* __restrict__ kb,
                                                u16* __restrict__ vb) {
    int s = blockIdx.x;
    int t = threadIdx.x, w = t >> 6, lane = t & 63;
    const float* row = qkv + (size_t)s * 3072;
    int d2 = lane & 31;
    float inv = exp2f(-(float)d2 * (13.287712379549449f / 32.0f));
    float ang = (float)s * inv;
    float cs = cosf(ang), sn = sinf(ang);
    for (int h = w; h < 48; h += 4) {
        float v = row[h * 64 + lane];
        if (h < 40) {
            float ss = v * v;
#pragma unroll
            for (int m = 32; m; m >>= 1) ss += __shfl_xor(ss, m);
            float rms = rsqrtf(ss * (1.0f / 64.0f) + 1e-6f);
            float wgt = (h < 32) ? qw[lane] : kw[lane];
            v = v * rms * wgt;
            float part = __shfl_xor(v, 32);
            float rot = (lane < 32) ? -part : part;
            v = v * cs + rot * sn;
            if (h < 32)
                qb[((size_t)h * 2048 + s) * 64 + lane] = f2bf(v);
            else
                kb[((size_t)(h - 32) * 2048 + s) * 64 + lane] = f2bf(v);
        } else {
            vb[((size_t)(h - 40) * 2048 + s) * 64 + lane] = f2bf(v);
        }
    }
}

// ---------------- V transpose: vb[kv][s][d] -> vt[kv][d][s] ----------------
__global__ __launch_bounds__(256) void transpose_v(const u16* __restrict__ vb,
                                                   u16* __restrict__ vt) {
    int kv = blockIdx.y;
    int s0 = blockIdx.x * 256;
    __shared__ __align__(16) u16 tile[64][256];
    int t = threadIdx.x;
    int sl = t >> 3;
    int d0 = (t & 7) * 8;
#pragma unroll
    for (int j = 0; j < 8; ++j) {
        int s = sl + j * 32;
        u16x8 v = *(const u16x8*)(vb + ((size_t)kv * 2048 + s0 + s) * 64 + d0);
#pragma unroll
        for (int e = 0; e < 8; ++e) tile[d0 + e][s] = v[e];
    }
    __syncthreads();
    int d = t >> 2;
    int so = (t & 3) * 64;
#pragma unroll
    for (int j = 0; j < 8; ++j) {
        int s_local = so + j * 8;
        *(u16x8*)(vt + ((size_t)kv * 64 + d) * 2048 + s0 + s_local) =
            *(const u16x8*)&tile[d][s_local];
    }
}

// ---------------- flash attention v2: swapped-operand 32x32 MFMA ----------------
// S[k][q] = mfma(K, Q): q = lane&31 -> softmax state lane-local.
// O^T[d][q] = mfma(V^T, P). P via cvt_pk + permlane32_swap.
// Running max clamped at 0 (diag score = |q|^2*0.125 ~ +8, so no accuracy loss;
// avoids the -1e30-init fma-residual inf/NaN path on fully-masked first tiles).
__global__ __launch_bounds__(256) void attn_fa2(const u16* __restrict__ qb,
                                                const u16* __restrict__ kb,
                                                const u16* __restrict__ vt,
                                                u16* __restrict__ ab) {
    const float C = 0.18033688011112042f;  // 0.125 * log2(e)
    int h = blockIdx.y, kv = h >> 2;
    int t = threadIdx.x, w = t >> 6, l = t & 63;
    int lq = l & 31, hi = l >> 5;
    int qlo = blockIdx.x * 128 + w * 32;
    __shared__ u16 sm[4][32][66];

    const u16* qrow = qb + ((size_t)h * 2048 + qlo + lq) * 64 + hi * 8;
    bf16x8 qf[4];
#pragma unroll
    for (int dk = 0; dk < 4; ++dk) qf[dk] = *(const bf16x8*)(qrow + dk * 16);

    f32x16 oa = {}, ob = {};
    float m = 0.f, lsum = 0.f;

    int kstart = qlo - 511; if (kstart < 0) kstart = 0;
    int kt0 = kstart >> 5, kt1 = qlo >> 5;
    const u16* kb_h = kb + (size_t)kv * 2048 * 64;
    const u16* vt_h = vt + (size_t)kv * 64 * 2048;

    for (int kt = kt0; kt <= kt1; ++kt) {
        int k0 = kt << 5;
        const u16* krow = kb_h + (size_t)(k0 + lq) * 64 + hi * 8;
        bf16x8 kf0 = *(const bf16x8*)(krow);
        bf16x8 kf1 = *(const bf16x8*)(krow + 16);
        bf16x8 kf2 = *(const bf16x8*)(krow + 32);
        bf16x8 kf3 = *(const bf16x8*)(krow + 48);
        const u16* vrow = vt_h + (size_t)lq * 2048 + k0 + hi * 8;
        bf16x8 va0 = *(const bf16x8*)(vrow);
        bf16x8 va1 = *(const bf16x8*)(vrow + 16);
        bf16x8 vb0 = *(const bf16x8*)(vrow + 32 * 2048);
        bf16x8 vb1 = *(const bf16x8*)(vrow + 32 * 2048 + 16);

        f32x16 s = {};
        s = MFMA32(kf0, qf[0], s);
        s = MFMA32(kf1, qf[1], s);
        s = MFMA32(kf2, qf[2], s);
        s = MFMA32(kf3, qf[3], s);

        bool edge = (k0 + 31 > qlo) || (qlo + 31 - k0 >= 512);
        if (edge) {
            int q = qlo + lq;
#pragma unroll
            for (int r = 0; r < 16; ++r) {
                int k = k0 + (r & 3) + 8 * (r >> 2) + 4 * hi;
                if (!((unsigned)(q - k) < 512u)) s[r] = -1e30f;
            }
        }
        float tm = s[0];
#pragma unroll
        for (int r = 1; r < 16; ++r) tm = fmaxf(tm, s[r]);
        tm = fmaxf(tm, __shfl_xor(tm, 32));
        float mnew = fmaxf(m, tm);          // m >= 0 always
        float mc = mnew * C;
        float sf = exp2f(m * C - mc);
        m = mnew;
        float p[16];
        float rs = 0.f;
#pragma unroll
        for (int r = 0; r < 16; ++r) {
            p[r] = exp2f(fmaf(s[r], C, -mc));
            rs += p[r];
        }
        rs += __shfl_xor(rs, 32);
        lsum = lsum * sf + rs;
#pragma unroll
        for (int r = 0; r < 16; ++r) { oa[r] *= sf; ob[r] *= sf; }

        u32 pk0 = cvtpk(p[0], p[1]),   pk1 = cvtpk(p[2], p[3]);
        u32 pk2 = cvtpk(p[4], p[5]),   pk3 = cvtpk(p[6], p[7]);
        u32 pk4 = cvtpk(p[8], p[9]),   pk5 = cvtpk(p[10], p[11]);
        u32 pk6 = cvtpk(p[12], p[13]), pk7 = cvtpk(p[14], p[15]);
        u32x2 r02 = __builtin_amdgcn_permlane32_swap(pk0, pk2, false, false);
        u32x2 r13 = __builtin_amdgcn_permlane32_swap(pk1, pk3, false, false);
        u32x2 r46 = __builtin_amdgcn_permlane32_swap(pk4, pk6, false, false);
        u32x2 r57 = __builtin_amdgcn_permlane32_swap(pk5, pk7, false, false);
        bf16x8 b0, b1;
        {
            u32* bp = (u32*)&b0;
            bp[0] = r02[0]; bp[1] = r13[0]; bp[2] = r02[1]; bp[3] = r13[1];
            u32* bq = (u32*)&b1;
            bq[0] = r46[0]; bq[1] = r57[0]; bq[2] = r46[1]; bq[3] = r57[1];
        }
        oa = MFMA32(va0, b0, oa);
        oa = MFMA32(va1, b1, oa);
        ob = MFMA32(vb0, b0, ob);
        ob = MFMA32(vb1, b1, ob);
    }

    float inv = 1.0f / lsum;
#pragma unroll
    for (int rp = 0; rp < 8; ++rp) {
        int r = rp * 2;
        int d = (r & 3) + 8 * (r >> 2) + 4 * hi;
        *(u32*)&sm[w][lq][d]      = cvtpk(oa[r] * inv, oa[r + 1] * inv);
        *(u32*)&sm[w][lq][d + 32] = cvtpk(ob[r] * inv, ob[r + 1] * inv);
    }
    asm volatile("s_waitcnt lgkmcnt(0)" ::: "memory");
    int qr = l >> 1, dbase = (l & 1) * 32;
    size_t orow = (size_t)(qlo + qr) * 2048 + h * 64 + dbase;
#pragma unroll
    for (int c2 = 0; c2 < 8; ++c2) {
        u32 w0 = *(const u32*)&sm[w][qr][dbase + c2 * 4];
        u32 w1 = *(const u32*)&sm[w][qr][dbase + c2 * 4 + 2];
        u32x2 val = { w0, w1 };
        *(u32x2*)(ab + orow + c2 * 4) = val;
    }
}

// ---------------- launch ----------------
extern "C" void kernel_launch(void* const* d_in, const int* in_sizes, int n_in,
                              void* d_out, int out_size, void* d_ws, size_t ws_size,
                              hipStream_t stream) {
    const float* x     = (const float*)d_in[0];
    const float* w_qkv = (const float*)d_in[1];
    const float* w_out = (const float*)d_in[2];
    const float* qw    = (const float*)d_in[3];
    const float* kw    = (const float*)d_in[4];
    float* out = (float*)d_out;

    char* ws = (char*)d_ws;
    u16*   x_b    = (u16*)(ws);
    u16*   wB     = (u16*)(ws + 8388608);
    float* qkv    = (float*)(ws + 20971520);
    u16*   q_b    = (u16*)(ws + 46137344);
    u16*   k_b    = (u16*)(ws + 54525952);
    u16*   v_b    = (u16*)(ws + 56623104);
    u16*   v_t    = (u16*)(ws + 58720256);
    u16*   attn_b = x_b;

    cvt_bf16<<<2048, 256, 0, stream>>>(x, x_b, 2048 * 2048 / 4);
    cvt_bf16<<<2048, 256, 0, stream>>>(w_qkv, wB, 3072 * 2048 / 4);
    gemm_bt<<<384, 256, 0, stream>>>(x_b, wB, qkv, 2048, 3072, 2048);
    qkv_post<<<2048, 256, 0, stream>>>(qkv, qw, kw, q_b, k_b, v_b);
    transpose_v<<<dim3(8, 8), 256, 0, stream>>>(v_b, v_t);
    attn_fa2<<<dim3(16, 32), 256, 0, stream>>>(q_b, k_b, v_t, attn_b);
    cvt_bf16<<<2048, 256, 0, stream>>>(w_out, wB, 2048 * 2048 / 4);
    gemm_bt<<<256, 256, 0, stream>>>(attn_b, wB, out, 2048, 2048, 2048);
}